// Round 13
// baseline (373.218 us; speedup 1.0000x reference)
//
#include <hip/hip_runtime.h>
#include <hip/hip_cooperative_groups.h>
#include <math.h>

namespace cg = cooperative_groups;

#define BB 32
#define TT 2048
#define CC 128
#define EE 256
#define LL 512
#define TYY 128
#define PP 24
#define NSTREAM 512     // 32 b x 16 chunks of 128 t
#define NSIN 512        // 32 b x 16 segs of 128 t
#define GRID 1024

// ws layout (float offsets):
//   pbuf  : float2[512][2][PP*64] = 3145728 floats at 0
//   tpart : [512][E]              = 131072         at 3145728
//   cemean: [E]                   = 256            at 3276800
//   cbase : [B][P][C]             = 98304          at 3277056
//   hbuf  : [B][L]                = 16384          at 3375360
#define WS_PBUF  0
#define WS_TPART 3145728
#define WS_CEM   3276800
#define WS_CBASE 3277056
#define WS_H     3375360

// ---------------------------------------------------------------------------
// Single cooperative kernel: 1024 blocks x 128 threads (4 blocks/CU).
// P0: blocks [0,512) stream X,M -> wave-private LDS float2 [P][64] RMW
//     (lane-exclusive cells, no atomics, no in-block barriers), flush to pbuf.
//     blocks [512,1024) sin-pool 128 t x 256 e each; last 8 also do cemean.
// P1: blocks [0,768) reduce 16 chunk-partials -> cbase[b][p][c].
// P2: blocks [0,256) = (b, l-octant): pooled (redundant, cheap) + h-slice
//     via partitioned w1 (64 KB/block).
// P3: blocks [0,256) = (b, c-group): y-slice via partitioned w2 (32 KB/block)
//     + output rows out[b, :, c16] with cbase gather.
// ---------------------------------------------------------------------------
__global__ __launch_bounds__(128) void k_fused(
        const float* __restrict__ ts,  const float* __restrict__ X,
        const int*   __restrict__ M,   const float* __restrict__ yt,
        const float* __restrict__ tw,  const float* __restrict__ tbias,
        const float* __restrict__ ce,  const float* __restrict__ w1,
        const float* __restrict__ b1,  const float* __restrict__ w2,
        const float* __restrict__ b2,  float* __restrict__ pbuf,
        float* __restrict__ tpart,     float* __restrict__ cemean,
        float* __restrict__ cbase,     float* __restrict__ hbuf,
        float* __restrict__ out) {
    cg::grid_group grid = cg::this_grid();
    __shared__ float smem[2 * PP * 64 * 2];        // 24 KB, reused per phase
    const int tid = threadIdx.x;
    const int blk = blockIdx.x;

    // ================= P0 =================
    if (blk < NSTREAM) {
        float2* acc = (float2*)smem;               // [2][PP*64]
        const int b  = blk >> 4;
        const int tB = (blk & 15) * 128;
        const int w  = tid >> 6;
        const int lane = tid & 63;
        const int c  = w * 64 + lane;
        float2* aw = acc + w * (PP * 64);
        for (int i = lane; i < PP * 64; i += 64) aw[i] = make_float2(0.f, 0.f);
        for (int g = 0; g < 16; ++g) {
            float xv[8]; int mv[8]; float tv[8];
#pragma unroll
            for (int k = 0; k < 8; ++k) {
                const int t = tB + g * 8 + k;
                const long r = ((long)(b * TT + t)) * CC + c;
                xv[k] = X[r]; mv[k] = M[r]; tv[k] = ts[b * TT + t];
            }
#pragma unroll
            for (int k = 0; k < 8; ++k) {
                const int p = ((int)floorf(tv[k])) % PP;   // ts >= 0
                const float m = (float)mv[k];
                float2 cell = aw[p * 64 + lane];
                cell.x = fmaf(xv[k], m, cell.x);
                cell.y += m;
                aw[p * 64 + lane] = cell;
            }
        }
        float2* pb = (float2*)pbuf + (long)blk * (2 * PP * 64) + w * (PP * 64);
        for (int i = lane; i < PP * 64; i += 64) pb[i] = aw[i];
    } else {
        // sin block: sb in [0,512)
        float* s_ts = smem;
        const int sb = blk - NSTREAM;
        const int b  = sb >> 4;
        const int tB = (sb & 15) * 128;
        s_ts[tid] = ts[b * TT + tB + tid];
        __syncthreads();
#pragma unroll
        for (int eh = 0; eh < 2; ++eh) {
            const int e = tid + eh * 128;
            const float w = tw[e], bb = tbias[e];
            float a = 0.f;
#pragma unroll 8
            for (int j = 0; j < 128; ++j) {
                const float v = fmaf(s_ts[j], w, bb);
                a += v + __sinf(v);
            }
            tpart[sb * EE + e] = a;
        }
        if (sb >= 504) {                           // cemean: 8 blocks x 32 e
            const int e = (sb - 504) * 32 + (tid >> 2);
            const int cq = tid & 3;
            float s = 0.f;
#pragma unroll 8
            for (int cc = cq * 32; cc < cq * 32 + 32; ++cc) s += ce[cc * EE + e];
            s += __shfl_down(s, 2);
            s += __shfl_down(s, 1);
            if (cq == 0) cemean[e] = s * (1.0f / CC);
        }
    }
    grid.sync();

    // ================= P1: cbase =================
    if (blk < BB * PP) {
        const int b = blk / PP;
        const int p = blk % PP;
        const int ch = tid >> 6, cl = tid & 63;
        float s = 0.f, n = 0.f;
#pragma unroll
        for (int k = 0; k < 16; ++k) {
            const float2 v = ((const float2*)pbuf)
                [((long)(b * 16 + k)) * (2 * PP * 64) + ch * (PP * 64) + p * 64 + cl];
            s += v.x; n += v.y;
        }
        cbase[(b * PP + p) * CC + tid] = s / fmaxf(n, 1.f);
    }
    grid.sync();

    // ================= P2: pooled + h =================
    if (blk < 256) {
        const int b = blk >> 3, q = blk & 7;
        float* s_pool = smem;                      // 256
#pragma unroll
        for (int eh = 0; eh < 2; ++eh) {
            const int e = tid + eh * 128;
            float sp = 0.f;
#pragma unroll
            for (int k = 0; k < 16; ++k) sp += tpart[(b * 16 + k) * EE + e];
            s_pool[e] = sp * (1.0f / TT) + cemean[e];
        }
        __syncthreads();
        const int l = q * 64 + (tid & 63);
        const int eh = tid >> 6;
        float ha = 0.f;
#pragma unroll 8
        for (int e = eh * 128; e < eh * 128 + 128; ++e)
            ha = fmaf(s_pool[e], w1[e * LL + l], ha);
        float* s_hp = smem + 256;
        s_hp[tid] = ha;
        __syncthreads();
        if (tid < 64)
            hbuf[b * LL + q * 64 + tid] =
                fmaxf(b1[q * 64 + tid] + s_hp[tid] + s_hp[tid + 64], 0.f);
    }
    grid.sync();

    // ================= P3: y + out =================
    if (blk < 256) {
        const int b = blk >> 3, cg2 = blk & 7;
        float* s_h = smem;                         // 512
        for (int i = tid; i < LL; i += 128) s_h[i] = hbuf[b * LL + i];
        __syncthreads();
        const int ci = tid & 15, lg = tid >> 4;    // 8 groups x 64 l
        const int c = cg2 * 16 + ci;
        float y = 0.f;
#pragma unroll 8
        for (int l = lg * 64; l < lg * 64 + 64; ++l)
            y = fmaf(s_h[l], w2[l * CC + c], y);
        float* s_yp = smem + 512;
        s_yp[tid] = y;
        __syncthreads();
        float* s_y = smem + 512 + 128;
        if (tid < 16) {
            float yy = b2[cg2 * 16 + tid];
#pragma unroll
            for (int g = 0; g < 8; ++g) yy += s_yp[tid + 16 * g];
            s_y[tid] = yy;
        }
        __syncthreads();
        for (int tyo = 0; tyo < 16; ++tyo) {
            const int ty = lg * 16 + tyo;
            const float v = yt[b * TYY + ty];
            int p = ((int)floorf(v)) % PP; if (p < 0) p += PP;
            out[((long)(b * TYY + ty)) * CC + c] =
                s_y[ci] + cbase[(b * PP + p) * CC + c];
        }
    }
}

extern "C" void kernel_launch(void* const* d_in, const int* in_sizes, int n_in,
                              void* d_out, int out_size, void* d_ws, size_t ws_size,
                              hipStream_t stream) {
    const float* ts   = (const float*)d_in[0];
    const float* X    = (const float*)d_in[1];
    const int*   M    = (const int*)  d_in[2];
    const float* yt   = (const float*)d_in[3];
    const float* tw   = (const float*)d_in[4];
    const float* tb   = (const float*)d_in[5];
    const float* ce   = (const float*)d_in[6];
    const float* w1   = (const float*)d_in[7];
    const float* b1   = (const float*)d_in[8];
    const float* w2   = (const float*)d_in[9];
    const float* b2   = (const float*)d_in[10];
    float* outp = (float*)d_out;

    float* ws     = (float*)d_ws;
    float* pbuf   = ws + WS_PBUF;
    float* tpart  = ws + WS_TPART;
    float* cemean = ws + WS_CEM;
    float* cbase  = ws + WS_CBASE;
    float* hbuf   = ws + WS_H;

    void* args[] = { (void*)&ts, (void*)&X, (void*)&M, (void*)&yt,
                     (void*)&tw, (void*)&tb, (void*)&ce, (void*)&w1,
                     (void*)&b1, (void*)&w2, (void*)&b2,
                     (void*)&pbuf, (void*)&tpart, (void*)&cemean,
                     (void*)&cbase, (void*)&hbuf, (void*)&outp };
    hipLaunchCooperativeKernel((void*)k_fused, dim3(GRID), dim3(128),
                               args, 0, stream);
}

// Round 14
// 28.233 us; speedup vs baseline: 13.2193x; 13.2193x over previous
//
#include <hip/hip_runtime.h>
#include <math.h>

#define BB 32
#define TT 2048
#define CC 128
#define EE 256
#define LL 512
#define TYY 128
#define PP 24
#define KS 8            // K-splits per batch row (blocks per b)
#define KT 256          // t's per block
#define NST 8           // stages per block (32 t each)
#define PITCH 40        // halfwords per W_lds row (80B: 16B-aligned)

// ws layout (floats):
//   pbuf  : [B*KS][P][256]   = 1572864  at 0        (j<128: sum, j>=128: cnt)
//   tpart : [B*KS*2][E]      = 131072   at 1572864
//   cemean: [E]              = 256      at 1703936
//   hbuf  : [B][L]           = 16384    at 1704192
#define WS_PBUF  0
#define WS_TPART 1572864
#define WS_CEM   1703936
#define WS_H     1704192

typedef __attribute__((ext_vector_type(8))) short bf16x8;
typedef __attribute__((ext_vector_type(4))) float f32x4;

__device__ __forceinline__ unsigned int pack_bf2(float a, float b) {
    unsigned int ua = __float_as_uint(a);
    unsigned int ub = __float_as_uint(b);
    ua = (ua + 0x7FFFu + ((ua >> 16) & 1u)) >> 16;           // RNE bf16 of a (low)
    ub = (ub + 0x7FFFu + ((ub >> 16) & 1u)) & 0xFFFF0000u;   // RNE bf16 of b (high)
    return ua | ub;
}

// ---------------------------------------------------------------------------
// K1: phase-bucket einsum via MFMA + fused sin-pool (R8 structure, best).
// grid = B*KS + 1 (257): block 256 computes channel-embed column mean.
// ---------------------------------------------------------------------------
__global__ __launch_bounds__(512) void k_main(const float* __restrict__ ts,
                                              const float* __restrict__ X,
                                              const int*   __restrict__ M,
                                              const float* __restrict__ tw,
                                              const float* __restrict__ tbias,
                                              const float* __restrict__ ce,
                                              float* __restrict__ pbuf,
                                              float* __restrict__ tpart,
                                              float* __restrict__ cemean) {
    __shared__ unsigned short wbuf[2][256 * PITCH];   // 40 KB
    __shared__ float s_ts[KT];
    __shared__ int   s_p[KT];

    const int tid = threadIdx.x;
    const int blk = blockIdx.x;

    if (blk == BB * KS) {                          // cemean block
        if (tid < EE) {
            float s = 0.0f;
#pragma unroll 16
            for (int c = 0; c < CC; ++c) s += ce[c * EE + tid];
            cemean[tid] = s * (1.0f / CC);
        }
        return;
    }

    const int b   = blk >> 3;
    const int ks  = blk & 7;
    const int tB  = ks * KT;

    if (tid < KT) {
        const float v = ts[b * TT + tB + tid];
        s_ts[tid] = v;
        s_p[tid] = ((int)floorf(v)) % PP;          // ts >= 0
    }

    // staging roles
    const int jc = tid & 63;
    const int tp = tid >> 6;                       // 0..7
    float xr0[2][2], xr1[2][2], xr2[2][2], xr3[2][2];   // [parity][it]
    int   mr0[2][2], mr1[2][2], mr2[2][2], mr3[2][2];

    // compute roles
    const int wv   = tid >> 6;
    const int lane = tid & 63;
    const int mt   = wv & 1;
    const int jt0  = (wv >> 1) * 4;
    const int mrow = mt * 16 + (lane & 15);
    const int kg   = lane >> 4;                    // 0..3
    const int k0   = kg * 8;
    const int n16  = lane & 15;

    // sin roles
    const int se = tid & 255;
    const int sh = tid >> 8;
    const float sw = tw[se];
    const float sb = tbias[se];
    float sacc = 0.0f;

    f32x4 acc[4];
#pragma unroll
    for (int jl = 0; jl < 4; ++jl) acc[jl] = (f32x4){0.f, 0.f, 0.f, 0.f};

    auto LOADS = [&](int s) {
        const int pr = s & 1;
#pragma unroll
        for (int it = 0; it < 2; ++it) {
            const int ttv = it * 16 + tp * 2;
            const long r0 = ((long)(b * TT + tB + s * 32 + ttv)) * CC;
            xr0[pr][it] = X[r0 + jc];
            xr1[pr][it] = X[r0 + jc + 64];
            xr2[pr][it] = X[r0 + CC + jc];
            xr3[pr][it] = X[r0 + CC + jc + 64];
            mr0[pr][it] = M[r0 + jc];
            mr1[pr][it] = M[r0 + jc + 64];
            mr2[pr][it] = M[r0 + CC + jc];
            mr3[pr][it] = M[r0 + CC + jc + 64];
        }
    };

    auto WRITES = [&](int s) {
        const int pr = s & 1;
        unsigned int* wb = (unsigned int*)wbuf[pr];
#pragma unroll
        for (int it = 0; it < 2; ++it) {
            const int ttv = it * 16 + tp * 2;
            const int th = ttv >> 1;
            const float xm00 = mr0[pr][it] ? xr0[pr][it] : 0.0f;
            const float xm10 = mr2[pr][it] ? xr2[pr][it] : 0.0f;
            const float xm01 = mr1[pr][it] ? xr1[pr][it] : 0.0f;
            const float xm11 = mr3[pr][it] ? xr3[pr][it] : 0.0f;
            wb[jc * 20 + th]         = pack_bf2(xm00, xm10);
            wb[(jc + 64) * 20 + th]  = pack_bf2(xm01, xm11);
            wb[(128 + jc) * 20 + th] = (mr0[pr][it] ? 0x3F80u : 0u) | (mr2[pr][it] ? 0x3F800000u : 0u);
            wb[(192 + jc) * 20 + th] = (mr1[pr][it] ? 0x3F80u : 0u) | (mr3[pr][it] ? 0x3F800000u : 0u);
        }
    };

    auto SINC = [&](int s) {
#pragma unroll
        for (int j = 0; j < 16; ++j) {
            const float v = fmaf(s_ts[s * 32 + sh * 16 + j], sw, sb);
            sacc += v + __sinf(v);
        }
    };

    LOADS(0);
    WRITES(0);
    LOADS(1);
    __syncthreads();                               // once: s_ts/s_p + wbuf[0]

    unsigned int au_all[NST][4];
#pragma unroll
    for (int s = 0; s < NST; ++s) {
        const int tb0 = s * 32 + k0;
        const int4 pA = *(const int4*)&s_p[tb0];
        const int4 pB = *(const int4*)&s_p[tb0 + 4];
        au_all[s][0] = (pA.x == mrow ? 0x3F80u : 0u) | (pA.y == mrow ? 0x3F800000u : 0u);
        au_all[s][1] = (pA.z == mrow ? 0x3F80u : 0u) | (pA.w == mrow ? 0x3F800000u : 0u);
        au_all[s][2] = (pB.x == mrow ? 0x3F80u : 0u) | (pB.y == mrow ? 0x3F800000u : 0u);
        au_all[s][3] = (pB.z == mrow ? 0x3F80u : 0u) | (pB.w == mrow ? 0x3F800000u : 0u);
    }

#pragma unroll
    for (int s = 0; s < NST; ++s) {
        if (s > 0) {
            asm volatile("s_waitcnt lgkmcnt(0)" ::: "memory");
            __builtin_amdgcn_s_barrier();          // no vmcnt drain
        }
        if (s + 2 < NST) LOADS(s + 2);
        {   // COMPUTE(s)
            union { unsigned int u[4]; bf16x8 v; } au;
            au.u[0] = au_all[s][0]; au.u[1] = au_all[s][1];
            au.u[2] = au_all[s][2]; au.u[3] = au_all[s][3];
#pragma unroll
            for (int jl = 0; jl < 4; ++jl) {
                const int jrow = (jt0 + jl) * 16 + n16;
                const bf16x8 bv = *(const bf16x8*)&wbuf[s & 1][jrow * PITCH + k0];
                acc[jl] = __builtin_amdgcn_mfma_f32_16x16x32_bf16(au.v, bv, acc[jl], 0, 0, 0);
            }
        }
        SINC(s);
        if (s + 1 < NST) WRITES(s + 1);
    }

    tpart[((b * KS + ks) * 2 + sh) * EE + se] = sacc;

    float* pbb = pbuf + ((long)blk) * PP * 256;
#pragma unroll
    for (int jl = 0; jl < 4; ++jl) {
#pragma unroll
        for (int r = 0; r < 4; ++r) {
            const int p = mt * 16 + kg * 4 + r;
            if (p < PP)
                pbb[p * 256 + (jt0 + jl) * 16 + n16] = acc[jl][r];
        }
    }
}

// ---------------------------------------------------------------------------
// K2: hidden layer, w1 PARTITIONED. grid = B*8 (256), block = 256.
// Block (b,q): pooled (redundant, 16KB tpart) + h[l in q*64..+64) via its
// private 64KB w1 slice. Writes hbuf.
// ---------------------------------------------------------------------------
__global__ __launch_bounds__(256) void k_hid(const float* __restrict__ tpart,
                                             const float* __restrict__ cemean,
                                             const float* __restrict__ w1,
                                             const float* __restrict__ b1,
                                             float* __restrict__ hbuf) {
    __shared__ float s_pool[EE];
    __shared__ float s_hp[256];
    const int b = blockIdx.x >> 3;
    const int q = blockIdx.x & 7;
    const int tid = threadIdx.x;

    {
        float sp = 0.0f;
#pragma unroll
        for (int k = 0; k < KS * 2; ++k) sp += tpart[(b * KS * 2 + k) * EE + tid];
        s_pool[tid] = sp * (1.0f / TT) + cemean[tid];
    }
    __syncthreads();

    const int l = q * 64 + (tid & 63);
    const int eq = tid >> 6;                       // 0..3, 64 e's each
    float ha = 0.0f;
#pragma unroll 16
    for (int e = eq * 64; e < eq * 64 + 64; ++e)
        ha = fmaf(s_pool[e], w1[e * LL + l], ha);
    s_hp[tid] = ha;
    __syncthreads();
    if (tid < 64)
        hbuf[b * LL + q * 64 + tid] =
            fmaxf(b1[q * 64 + tid] + s_hp[tid] + s_hp[tid + 64]
                  + s_hp[tid + 128] + s_hp[tid + 192], 0.0f);
}

// ---------------------------------------------------------------------------
// K3: output layer, w2 PARTITIONED + own cbase c-slice from pbuf + scatter.
// grid = B*8 (256), block = 256. Block (b,co): c in [co*16, +16).
// ---------------------------------------------------------------------------
__global__ __launch_bounds__(256) void k_out(const float* __restrict__ hbuf,
                                             const float* __restrict__ w2,
                                             const float* __restrict__ b2,
                                             const float* __restrict__ pbuf,
                                             const float* __restrict__ yt,
                                             float* __restrict__ out) {
    __shared__ float s_h[LL];
    __shared__ float s_yp[256];
    __shared__ float s_y[16];
    __shared__ float s_cb[PP * 16];
    __shared__ int   s_ph[TYY];
    const int b  = blockIdx.x >> 3;
    const int co = blockIdx.x & 7;
    const int tid = threadIdx.x;

    for (int i = tid; i < LL; i += 256) s_h[i] = hbuf[b * LL + i];
    if (tid < TYY) {
        const float v = yt[b * TYY + tid];
        int p = ((int)floorf(v)) % PP; if (p < 0) p += PP;
        s_ph[tid] = p;
    }
    __syncthreads();

    // y partials: c16 = tid&15, lg = tid>>4 over 32 l's each
    {
        const int c16 = tid & 15;
        const int lg = tid >> 4;
        float y = 0.0f;
#pragma unroll 8
        for (int l = lg * 32; l < lg * 32 + 32; ++l)
            y = fmaf(s_h[l], w2[l * CC + co * 16 + c16], y);
        s_yp[tid] = y;
    }
    // cbase c-slice: 384 cells (p, c16), each sums 8 chunk partials
    for (int i = tid; i < PP * 16; i += 256) {
        const int p = i >> 4;
        const int c = co * 16 + (i & 15);
        float s = 0.0f, n = 0.0f;
#pragma unroll
        for (int k = 0; k < KS; ++k) {
            const float* pb = pbuf + ((long)(b * KS + k)) * PP * 256 + p * 256;
            s += pb[c];
            n += pb[128 + c];
        }
        s_cb[i] = s / fmaxf(n, 1.0f);
    }
    __syncthreads();
    if (tid < 16) {
        float yy = b2[co * 16 + tid];
#pragma unroll
        for (int g = 0; g < 16; ++g) yy += s_yp[tid + 16 * g];
        s_y[tid] = yy;
    }
    __syncthreads();

    for (int i = tid; i < TYY * 16; i += 256) {
        const int ty = i >> 4;
        const int ci = i & 15;
        out[((long)(b * TYY + ty)) * CC + co * 16 + ci] =
            s_y[ci] + s_cb[s_ph[ty] * 16 + ci];
    }
}

extern "C" void kernel_launch(void* const* d_in, const int* in_sizes, int n_in,
                              void* d_out, int out_size, void* d_ws, size_t ws_size,
                              hipStream_t stream) {
    const float* ts   = (const float*)d_in[0];
    const float* X    = (const float*)d_in[1];
    const int*   M    = (const int*)  d_in[2];
    const float* yt   = (const float*)d_in[3];
    const float* tw   = (const float*)d_in[4];
    const float* tb   = (const float*)d_in[5];
    const float* ce   = (const float*)d_in[6];
    const float* w1   = (const float*)d_in[7];
    const float* b1   = (const float*)d_in[8];
    const float* w2   = (const float*)d_in[9];
    const float* b2   = (const float*)d_in[10];
    float* out = (float*)d_out;

    float* ws     = (float*)d_ws;
    float* pbuf   = ws + WS_PBUF;
    float* tpart  = ws + WS_TPART;
    float* cemean = ws + WS_CEM;
    float* hbuf   = ws + WS_H;

    k_main<<<BB * KS + 1, 512, 0, stream>>>(ts, X, M, tw, tb, ce, pbuf, tpart, cemean);
    k_hid<<<BB * 8, 256, 0, stream>>>(tpart, cemean, w1, b1, hbuf);
    k_out<<<BB * 8, 256, 0, stream>>>(hbuf, w2, b2, pbuf, yt, out);
}